// Round 4
// baseline (277.884 us; speedup 1.0000x reference)
//
#include <hip/hip_runtime.h>

// MoE router, fp32: x = token_inputs * jitter; logits = x @ w + b;
// softmax over E=64; keep top-2 probs, zero rest. Tokens=32768, H=2048, E=64.
//
// Register-tiled outer product: thread = 8 tok x 8 exp (64 accs), so each k
// needs 4x ds_read_b128 (8 x-floats + 8 w-floats) for 64 FMAs -> 0.25
// floats/FMA of LDS return bandwidth (the round-3 kernel paid 1.125).
// Block = 4 waves / 64 tokens; K-split 4 across waves; ALL LDS wave-private
// -> no barriers in the main loop (per-wave DS ops execute in order, so a
// single buffer with read->write->read is safe). One barrier total, for the
// K-split logit reduction.

#define H     2048
#define E     64
#define TOKB  64
#define KPW   512            // k per wave (K-split 4)
#define KC    32             // k per chunk
#define NCH   (KPW / KC)     // 16

__global__ __launch_bounds__(256, 2)
void router_kernel(const float* __restrict__ xg,
                   const float* __restrict__ jg,
                   const float* __restrict__ wg,
                   const float* __restrict__ bg,
                   float* __restrict__ out)
{
    // per wave: [0] = xs (transposed [k][t], col = t ^ (k&56)), [1] = ws [k][e]
    __shared__ float lds[4][2][KC][64];          // 64 KB

    const int tid  = threadIdx.x;
    const int wv   = tid >> 6;
    const int lane = tid & 63;
    const int t0   = (lane >> 3) << 3;           // token group base (0..56)
    const int e0   = (lane & 7) << 3;            // expert group base (0..56)
    const size_t blockTok = (size_t)blockIdx.x * TOKB;

    float (*xsw)[64] = lds[wv][0];
    float (*wsw)[64] = lds[wv][1];

    // staging decode: x/j: lane covers token (lane>>3)+8j, k-f4 (lane&7), j=0..7
    //                 w  : lane covers row (lane>>4)+4j, col-f4 (lane&15)
    const int sl_tok = lane >> 3;
    const int sl_kf4 = lane & 7;
    const int sl_xc  = (sl_kf4 << 2) & 56;       // xs write swizzle const
    const int sw_row = lane >> 4;
    const int sw_cf4 = lane & 15;

    const float* xbase = xg + (blockTok + sl_tok) * H + wv * KPW + (sl_kf4 << 2);
    const float* jbase = jg + (blockTok + sl_tok) * H + wv * KPW + (sl_kf4 << 2);
    const float* wbase = wg + ((size_t)wv * KPW + sw_row) * E + (sw_cf4 << 2);

    float acc[8][8];
#pragma unroll
    for (int i = 0; i < 8; ++i)
#pragma unroll
        for (int j = 0; j < 8; ++j) acc[i][j] = 0.f;

    float4 xv[8], jv[8], wv4[8];

#define STAGE_LOAD(c) do {                                                  \
    _Pragma("unroll")                                                       \
    for (int j = 0; j < 8; ++j) {                                           \
        xv[j]  = *(const float4*)(xbase + (size_t)(c) * KC + j * 8 * H);    \
        jv[j]  = *(const float4*)(jbase + (size_t)(c) * KC + j * 8 * H);    \
        wv4[j] = *(const float4*)(wbase + (size_t)(c) * KC * E + j * 4 * E);\
    }                                                                       \
} while (0)

#define STAGE_WRITE() do {                                                  \
    _Pragma("unroll")                                                       \
    for (int j = 0; j < 8; ++j) {                                           \
        const int tok = sl_tok + 8 * j;                                     \
        const int col = tok ^ sl_xc;                                        \
        const int kr  = sl_kf4 << 2;                                        \
        xsw[kr + 0][col] = xv[j].x * jv[j].x;                               \
        xsw[kr + 1][col] = xv[j].y * jv[j].y;                               \
        xsw[kr + 2][col] = xv[j].z * jv[j].z;                               \
        xsw[kr + 3][col] = xv[j].w * jv[j].w;                               \
        *(float4*)&wsw[sw_row + 4 * j][sw_cf4 << 2] = wv4[j];               \
    }                                                                       \
} while (0)

#define COMPUTE() do {                                                      \
    _Pragma("unroll")                                                       \
    for (int k = 0; k < KC; ++k) {                                          \
        const int xc = t0 ^ (k & 56);                                       \
        float xr[8], wr[8];                                                 \
        *(float4*)&xr[0] = *(const float4*)&xsw[k][xc];                     \
        *(float4*)&xr[4] = *(const float4*)&xsw[k][xc + 4];                 \
        *(float4*)&wr[0] = *(const float4*)&wsw[k][e0];                     \
        *(float4*)&wr[4] = *(const float4*)&wsw[k][e0 + 4];                 \
        _Pragma("unroll")                                                   \
        for (int i = 0; i < 8; ++i)                                         \
            _Pragma("unroll")                                               \
            for (int j = 0; j < 8; ++j)                                     \
                acc[i][j] = fmaf(xr[i], wr[j], acc[i][j]);                  \
    }                                                                       \
} while (0)

    // prologue: chunk 0 -> LDS, chunk 1 -> regs
    STAGE_LOAD(0);
    STAGE_WRITE();
    STAGE_LOAD(1);

    // steady state: compute(c) | write(c+1) | load(c+2)   [no barriers]
#pragma unroll 1
    for (int c = 0; c < NCH - 2; ++c) {
        COMPUTE();
        STAGE_WRITE();
        STAGE_LOAD(c + 2);
    }
    COMPUTE();
    STAGE_WRITE();
    COMPUTE();

    // ---- K-split reduction + softmax + top-2 ----
    // overlay partial buffer on this wave's own LDS region (in-order safe)
    float (*part)[64][64] = (float (*)[64][64])lds;   // part[wave][t][col]
    // f4-granular row-rotate: logical e-f4 f stored at f4col (f + t) & 15
#pragma unroll
    for (int i = 0; i < 8; ++i) {
        const int t = t0 + i;
#pragma unroll
        for (int jf = 0; jf < 2; ++jf) {
            const int cf4 = ((e0 >> 2) + jf + t) & 15;
            float4 v;
            v.x = acc[i][jf * 4 + 0]; v.y = acc[i][jf * 4 + 1];
            v.z = acc[i][jf * 4 + 2]; v.w = acc[i][jf * 4 + 3];
            *(float4*)&part[wv][t][cf4 << 2] = v;
        }
    }
    __syncthreads();

    // 4 threads per token; thread q handles experts [16q, 16q+16)
    const int t = tid >> 2;
    const int q = tid & 3;

    float l[16];
#pragma unroll
    for (int i = 0; i < 4; ++i) {
        const int cf4 = (q * 4 + i + t) & 15;
        const float4 s0 = *(const float4*)&part[0][t][cf4 << 2];
        const float4 s1 = *(const float4*)&part[1][t][cf4 << 2];
        const float4 s2 = *(const float4*)&part[2][t][cf4 << 2];
        const float4 s3 = *(const float4*)&part[3][t][cf4 << 2];
        const float4 bb = *(const float4*)(bg + q * 16 + i * 4);
        l[i * 4 + 0] = s0.x + s1.x + s2.x + s3.x + bb.x;
        l[i * 4 + 1] = s0.y + s1.y + s2.y + s3.y + bb.y;
        l[i * 4 + 2] = s0.z + s1.z + s2.z + s3.z + bb.z;
        l[i * 4 + 3] = s0.w + s1.w + s2.w + s3.w + bb.w;
    }

    // local top-2 (strict '>' ascending keeps lowest index on ties)
    float p1 = l[0]; int i1 = q * 16;
    float p2 = -3.0e38f; int i2 = q * 16;
#pragma unroll
    for (int i = 1; i < 16; ++i) {
        const int e = q * 16 + i;
        if (l[i] > p1)      { p2 = p1; i2 = i1; p1 = l[i]; i1 = e; }
        else if (l[i] > p2) { p2 = l[i]; i2 = e; }
    }

    // merge across the token's 4 threads (width 4)
#pragma unroll
    for (int m = 1; m <= 2; m <<= 1) {
        const float q1 = __shfl_xor(p1, m, 4);
        const int   k1 = __shfl_xor(i1, m, 4);
        const float q2 = __shfl_xor(p2, m, 4);
        const int   k2 = __shfl_xor(i2, m, 4);
        const bool  bw = (q1 > p1) || (q1 == p1 && k1 < i1);
        const float f1 = bw ? q1 : p1;  const int fi1 = bw ? k1 : i1;
        const float lo = bw ? p1 : q1;  const int loi = bw ? i1 : k1;
        const float sn = bw ? q2 : p2;  const int sni = bw ? k2 : i2;
        const bool  rw = (lo > sn) || (lo == sn && loi < sni);
        p2 = rw ? lo : sn;  i2 = rw ? loi : sni;
        p1 = f1;            i1 = fi1;
    }

    // softmax denominator over all 64 experts
    float d = 0.f;
#pragma unroll
    for (int i = 0; i < 16; ++i) d += __expf(l[i] - p1);
#pragma unroll
    for (int m = 1; m <= 2; m <<= 1) d += __shfl_xor(d, m, 4);

    const float inv = 1.f / d;                 // top-1 prob
    const float v2  = __expf(p2 - p1) * inv;   // top-2 prob

    // masked store: 16 experts per thread, coalesced float4s
    float* op = out + (blockTok + t) * (size_t)E + q * 16;
#pragma unroll
    for (int i = 0; i < 4; ++i) {
        float4 v;
        const int eb = q * 16 + i * 4;
        v.x = (eb + 0 == i1) ? inv : (eb + 0 == i2) ? v2 : 0.f;
        v.y = (eb + 1 == i1) ? inv : (eb + 1 == i2) ? v2 : 0.f;
        v.z = (eb + 2 == i1) ? inv : (eb + 2 == i2) ? v2 : 0.f;
        v.w = (eb + 3 == i1) ? inv : (eb + 3 == i2) ? v2 : 0.f;
        *(float4*)(op + i * 4) = v;
    }
}

extern "C" void kernel_launch(void* const* d_in, const int* in_sizes, int n_in,
                              void* d_out, int out_size, void* d_ws, size_t ws_size,
                              hipStream_t stream)
{
    const float* x   = (const float*)d_in[0];
    const float* jit = (const float*)d_in[1];
    const float* w   = (const float*)d_in[2];
    const float* b   = (const float*)d_in[3];
    float*       out = (float*)d_out;

    const int n_tok = in_sizes[0] / H;     // 32768
    dim3 grid(n_tok / TOKB), block(256);
    hipLaunchKernelGGL(router_kernel, grid, block, 0, stream, x, jit, w, b, out);
}

// Round 5
// 213.021 us; speedup vs baseline: 1.3045x; 1.3045x over previous
//
#include <hip/hip_runtime.h>

// MoE router, fp32-accurate via bf16-split MFMA.
// x = token_inputs * jitter; logits = x @ w + b; softmax E=64; top-2 mask.
// Tokens = 32768, H = 2048, E = 64.
//
// v = hi + lo (both bf16 RNE); x.w ~= xh.wh + xl.wh + xh.wl  (drop lo.lo,
// rel err ~2^-16 -> logit err ~1e-5, better than the fp32 k-reorder that
// already passed). 3x mfma_f32_16x16x32_bf16 per tile.
//
// Layout note: A and B share the same slot->k map, so packing BOTH operands
// with the same contiguous-8-per-lane-group order is correct regardless of
// the hardware's internal k permutation. C/D map (verified): lane l, reg r
// -> row=(l>>4)*4+r, col=l&15.
//
// Structure: block = 4 waves = 64 tokens; wave owns 16 tokens x all 64
// experts. NO LDS, NO barriers. A-frags built in registers from prefetched
// x*jitter; B-frags read directly from L2-resident w_hiT/w_loT (bf16,
// [64 e][2048 k], produced by a tiny pre-kernel into d_ws).

#define H 2048
#define E 64

typedef __attribute__((ext_vector_type(8))) short bf16x8;
typedef __attribute__((ext_vector_type(4))) float f32x4;

__device__ inline ushort f2bf_rne(float f) {
    union { float f; unsigned u; } c; c.f = f;
    const unsigned r = (c.u + 0x7FFFu + ((c.u >> 16) & 1u)) >> 16;
    return (ushort)r;
}
__device__ inline float bf2f(ushort h) {
    union { unsigned u; float f; } c; c.u = ((unsigned)h) << 16;
    return c.f;
}

// ---- pre-kernel: w [2048 k][64 e] f32 -> w_hiT/w_loT [64 e][2048 k] bf16 ----
__global__ __launch_bounds__(256)
void wsplit_kernel(const float* __restrict__ w,
                   ushort* __restrict__ whiT,
                   ushort* __restrict__ wloT)
{
    const int id = blockIdx.x * 256 + threadIdx.x;  // 0..32767
    const int e4 = (id & 15) << 2;                  // expert base 0..60
    const int k  = id >> 4;                         // 0..2047
    const float4 v = *(const float4*)(w + (size_t)k * E + e4);
    const float vv[4] = {v.x, v.y, v.z, v.w};
#pragma unroll
    for (int i = 0; i < 4; ++i) {
        const ushort hi = f2bf_rne(vv[i]);
        const float  lo = vv[i] - bf2f(hi);
        whiT[(size_t)(e4 + i) * H + k] = hi;
        wloT[(size_t)(e4 + i) * H + k] = f2bf_rne(lo);
    }
}

// ---- main kernel ----
__global__ __launch_bounds__(256)
void router_kernel(const float* __restrict__ xg,
                   const float* __restrict__ jg,
                   const ushort* __restrict__ whiT,
                   const ushort* __restrict__ wloT,
                   const float* __restrict__ bias,
                   float* __restrict__ out)
{
    const int tid  = threadIdx.x;
    const int wv   = tid >> 6;
    const int lane = tid & 63;
    const int ln   = lane & 15;      // A row (token-in-tile) / B col (expert-in-tile)
    const int g    = lane >> 4;      // k-group
    const size_t tokBase = (size_t)blockIdx.x * 64 + (size_t)wv * 16;

    const float*  xp  = xg + (tokBase + ln) * H + g * 8;
    const float*  jp  = jg + (tokBase + ln) * H + g * 8;
    const ushort* bh0 = whiT + (size_t)ln * H + g * 8;
    const ushort* bl0 = wloT + (size_t)ln * H + g * 8;

    f32x4 acc[4];
#pragma unroll
    for (int n = 0; n < 4; ++n) acc[n] = (f32x4){0.f, 0.f, 0.f, 0.f};

    // prefetch k-step 0
    float4 x0 = *(const float4*)(xp);
    float4 x1 = *(const float4*)(xp + 4);
    float4 j0 = *(const float4*)(jp);
    float4 j1 = *(const float4*)(jp + 4);

#pragma unroll 2
    for (int ks = 0; ks < 64; ++ks) {
        // prefetch next k-step (clamped: last iter re-reads, L1-hot, unused)
        const int nk = (ks < 63) ? ks + 1 : 63;
        const float* xq = xp + nk * 32;
        const float* jq = jp + nk * 32;
        const float4 nx0 = *(const float4*)(xq);
        const float4 nx1 = *(const float4*)(xq + 4);
        const float4 nj0 = *(const float4*)(jq);
        const float4 nj1 = *(const float4*)(jq + 4);

        // build A-frags: 8 products -> hi/lo bf16
        float p[8];
        p[0] = x0.x * j0.x; p[1] = x0.y * j0.y; p[2] = x0.z * j0.z; p[3] = x0.w * j0.w;
        p[4] = x1.x * j1.x; p[5] = x1.y * j1.y; p[6] = x1.z * j1.z; p[7] = x1.w * j1.w;
        bf16x8 ah, al;
#pragma unroll
        for (int i = 0; i < 8; ++i) {
            const ushort hi = f2bf_rne(p[i]);
            ah[i] = (short)hi;
            al[i] = (short)f2bf_rne(p[i] - bf2f(hi));
        }

        const int ko = ks * 32;
#pragma unroll
        for (int n = 0; n < 4; ++n) {
            const bf16x8 bh = *(const bf16x8*)(bh0 + (size_t)n * 16 * H + ko);
            const bf16x8 bl = *(const bf16x8*)(bl0 + (size_t)n * 16 * H + ko);
            acc[n] = __builtin_amdgcn_mfma_f32_16x16x32_bf16(ah, bh, acc[n], 0, 0, 0);
            acc[n] = __builtin_amdgcn_mfma_f32_16x16x32_bf16(al, bh, acc[n], 0, 0, 0);
            acc[n] = __builtin_amdgcn_mfma_f32_16x16x32_bf16(ah, bl, acc[n], 0, 0, 0);
        }

        x0 = nx0; x1 = nx1; j0 = nj0; j1 = nj1;
    }

    // ---- epilogue: softmax + top-2 per token, within 16-lane groups ----
    const float b0 = bias[ln], b1 = bias[16 + ln], b2 = bias[32 + ln], b3 = bias[48 + ln];
    float* outw = out + tokBase * E;

#pragma unroll
    for (int r = 0; r < 4; ++r) {
        // token = tokBase + g*4 + r ; this lane holds experts {0,16,32,48}+ln
        const float v0 = acc[0][r] + b0;
        const float v1 = acc[1][r] + b1;
        const float v2 = acc[2][r] + b2;
        const float v3 = acc[3][r] + b3;

        // local top-2 (ascending expert id; strict '>' keeps lowest index on ties)
        float p1 = v0; int i1 = ln;
        float p2 = -3.0e38f; int i2 = ln;
        if (v1 > p1)      { p2 = p1; i2 = i1; p1 = v1; i1 = 16 + ln; }
        else if (v1 > p2) { p2 = v1; i2 = 16 + ln; }
        if (v2 > p1)      { p2 = p1; i2 = i1; p1 = v2; i1 = 32 + ln; }
        else if (v2 > p2) { p2 = v2; i2 = 32 + ln; }
        if (v3 > p1)      { p2 = p1; i2 = i1; p1 = v3; i1 = 48 + ln; }
        else if (v3 > p2) { p2 = v3; i2 = 48 + ln; }

        // butterfly top-2 merge across the 16-lane group
#pragma unroll
        for (int m = 1; m <= 8; m <<= 1) {
            const float q1 = __shfl_xor(p1, m, 16);
            const int   k1 = __shfl_xor(i1, m, 16);
            const float q2 = __shfl_xor(p2, m, 16);
            const int   k2 = __shfl_xor(i2, m, 16);
            const bool  bw = (q1 > p1) || (q1 == p1 && k1 < i1);
            const float f1 = bw ? q1 : p1;  const int fi1 = bw ? k1 : i1;
            const float lo = bw ? p1 : q1;  const int loi = bw ? i1 : k1;
            const float sn = bw ? q2 : p2;  const int sni = bw ? k2 : i2;
            const bool  rw = (lo > sn) || (lo == sn && loi < sni);
            p2 = rw ? lo : sn;  i2 = rw ? loi : sni;
            p1 = f1;            i1 = fi1;
        }
        // p1 = max logit (top-1), p2 = second

        float d = __expf(v0 - p1) + __expf(v1 - p1) + __expf(v2 - p1) + __expf(v3 - p1);
#pragma unroll
        for (int m = 1; m <= 8; m <<= 1) d += __shfl_xor(d, m, 16);

        const float inv = 1.f / d;                 // top-1 prob
        const float w2  = __expf(p2 - p1) * inv;   // top-2 prob

        const size_t trow = (size_t)(g * 4 + r) * E;
        outw[trow +      ln] = (     ln == i1) ? inv : (     ln == i2) ? w2 : 0.f;
        outw[trow + 16 + ln] = (16 + ln == i1) ? inv : (16 + ln == i2) ? w2 : 0.f;
        outw[trow + 32 + ln] = (32 + ln == i1) ? inv : (32 + ln == i2) ? w2 : 0.f;
        outw[trow + 48 + ln] = (48 + ln == i1) ? inv : (48 + ln == i2) ? w2 : 0.f;
    }
}

extern "C" void kernel_launch(void* const* d_in, const int* in_sizes, int n_in,
                              void* d_out, int out_size, void* d_ws, size_t ws_size,
                              hipStream_t stream)
{
    const float* x   = (const float*)d_in[0];
    const float* jit = (const float*)d_in[1];
    const float* w   = (const float*)d_in[2];
    const float* b   = (const float*)d_in[3];
    float*       out = (float*)d_out;

    ushort* whiT = (ushort*)d_ws;              // 64*2048*2B = 256 KB
    ushort* wloT = whiT + (size_t)E * H;       // next 256 KB

    // split+transpose w (runs every call; deterministic)
    hipLaunchKernelGGL(wsplit_kernel, dim3(128), dim3(256), 0, stream, w, whiT, wloT);

    const int n_tok = in_sizes[0] / H;         // 32768
    dim3 grid(n_tok / 64), block(256);
    hipLaunchKernelGGL(router_kernel, grid, block, 0, stream,
                       x, jit, whiT, wloT, b, out);
}

// Round 6
// 121.916 us; speedup vs baseline: 2.2793x; 1.7473x over previous
//
#include <hip/hip_runtime.h>

// MoE router, fp32-accurate via bf16-split MFMA (R5 math, verified absmax 9.8e-4).
// x = token_inputs * jitter; logits = x @ w + b; softmax E=64; top-2 mask.
// Tokens = 32768, H = 2048, E = 64.
//
// R6 structure: wave = 16 tokens x 64 experts, block = 4 waves / 64 tokens.
// A-side: x,j loaded coalesced (8 lanes x 16B contiguous per row), product
//   staged in wave-private LDS (2KB/chunk, dbuf, XOR swizzle f^=tok&7),
//   frags via ds_read_b128. No barriers anywhere (wave-private, DS in-order).
// B-side: pre-kernel packs w hi/lo into MFMA-fragment-linear layout
//   bp[frag][lane][8] -> every B load is a wave-contiguous 1KB dwordx4, L2-hot.
// Pipeline: named even/odd register sets, k-loop unrolled x2 (no runtime
//   array indexing -> no scratch), loads issued 1.5-2 k-steps ahead.

#define H   2048
#define E   64
#define NKS 64          // k-steps of 32

typedef __attribute__((ext_vector_type(8))) short bf16x8;
typedef __attribute__((ext_vector_type(4))) float f32x4;

__device__ inline ushort f2bf_rne(float f) {
    union { float f; unsigned u; } c; c.f = f;
    const unsigned r = (c.u + 0x7FFFu + ((c.u >> 16) & 1u)) >> 16;
    return (ushort)r;
}
__device__ inline float bf2f(ushort h) {
    union { unsigned u; float f; } c; c.u = ((unsigned)h) << 16;
    return c.f;
}

// ---- pre-kernel: pack w into fragment-linear hi/lo bf16 ----
// frag fi = (ks*4 + n)*2 + p ; element: lane(g,c), slot s ->
//   w[ks*32 + g*8 + s][n*16 + c]   (A and B share the same slot->k map,
//   so contiguous-8 packing is correct independent of HW's internal order)
__global__ __launch_bounds__(256)
void wpack_kernel(const float* __restrict__ w, ushort* __restrict__ bp)
{
    const int t    = blockIdx.x * 256 + threadIdx.x;  // 0..16383
    const int lane = t & 63;
    const int n    = (t >> 6) & 3;
    const int ks   = t >> 8;                          // 0..63
    const int c    = lane & 15, g = lane >> 4;

    const float* src = w + (size_t)(ks * 32 + g * 8) * E + n * 16 + c;
    bf16x8 vh, vl;
#pragma unroll
    for (int s = 0; s < 8; ++s) {
        const float  v = src[(size_t)s * E];
        const ushort h = f2bf_rne(v);
        vh[s] = (short)h;
        vl[s] = (short)f2bf_rne(v - bf2f(h));
    }
    ushort* d = bp + ((size_t)(ks * 4 + n) * 2 * 64 + lane) * 8;
    *(bf16x8*)d         = vh;     // p=0 (hi)
    *(bf16x8*)(d + 512) = vl;     // p=1 (lo), next frag
}

// ---- main kernel ----
__global__ __launch_bounds__(256, 2)
void router_kernel(const float* __restrict__ xg,
                   const float* __restrict__ jg,
                   const ushort* __restrict__ bp,
                   const float* __restrict__ bias,
                   float* __restrict__ out)
{
    // wave-private staging of x*j: element (tok, f4) at prod[wv][buf][tok][f4 ^ (tok&7)]
    __shared__ __align__(16) float prod[4][2][16][8][4];   // 16 KB

    const int tid  = threadIdx.x;
    const int wv   = tid >> 6;
    const int lane = tid & 63;
    const int ln   = lane & 15;          // token-in-tile / expert col
    const int g    = lane >> 4;          // k-group
    const size_t tokBase = (size_t)blockIdx.x * 64 + (size_t)wv * 16;

    // staging coords: lane covers (tok = stok, stok+8), f4 = sf, per chunk
    const int stok = lane >> 3;          // 0..7
    const int sf   = lane & 7;           // 0..7
    const int swf  = sf ^ (stok & 7);    // same for stok and stok+8
    const float* xb = xg + (tokBase + stok) * H + sf * 4;
    const float* jb = jg + (tokBase + stok) * H + sf * 4;

    f32x4 acc[4];
#pragma unroll
    for (int n = 0; n < 4; ++n) acc[n] = (f32x4){0.f, 0.f, 0.f, 0.f};

    float4 xe0, xe1, je0, je1;   // even-chunk regs
    float4 xo0, xo1, jo0, jo1;   // odd-chunk regs
    bf16x8 BH0[4], BL0[4], BH1[4], BL1[4];

#define LOAD_XJ(X0, J0, X1, J1, c) do {                         \
        const size_t o_ = (size_t)(c) * 32;                     \
        X0 = *(const float4*)(xb + o_);                         \
        J0 = *(const float4*)(jb + o_);                         \
        X1 = *(const float4*)(xb + o_ + 8 * (size_t)H);         \
        J1 = *(const float4*)(jb + o_ + 8 * (size_t)H);         \
    } while (0)

#define WRITE_STAGE(b, X0, J0, X1, J1) do {                     \
        float4 q0, q1;                                          \
        q0.x = X0.x * J0.x; q0.y = X0.y * J0.y;                 \
        q0.z = X0.z * J0.z; q0.w = X0.w * J0.w;                 \
        q1.x = X1.x * J1.x; q1.y = X1.y * J1.y;                 \
        q1.z = X1.z * J1.z; q1.w = X1.w * J1.w;                 \
        *(float4*)&prod[wv][b][stok][swf][0]     = q0;          \
        *(float4*)&prod[wv][b][stok + 8][swf][0] = q1;          \
    } while (0)

#define LOAD_B(BH, BL, ks) do {                                             \
        _Pragma("unroll")                                                   \
        for (int n_ = 0; n_ < 4; ++n_) {                                    \
            const ushort* p_ = bp + (size_t)((ks) * 4 + n_) * 1024 + lane * 8; \
            BH[n_] = *(const bf16x8*)p_;                                    \
            BL[n_] = *(const bf16x8*)(p_ + 512);                            \
        }                                                                   \
    } while (0)

#define KSTEP(rb, BH, BL) do {                                              \
        const int f0s_ = (g * 2) ^ (ln & 7);                                \
        float p_[8];                                                        \
        *(float4*)&p_[0] = *(const float4*)&prod[wv][rb][ln][f0s_][0];      \
        *(float4*)&p_[4] = *(const float4*)&prod[wv][rb][ln][f0s_ ^ 1][0];  \
        bf16x8 ah_, al_;                                                    \
        _Pragma("unroll")                                                   \
        for (int i_ = 0; i_ < 8; ++i_) {                                    \
            const ushort h_ = f2bf_rne(p_[i_]);                             \
            ah_[i_] = (short)h_;                                            \
            al_[i_] = (short)f2bf_rne(p_[i_] - bf2f(h_));                   \
        }                                                                   \
        _Pragma("unroll")                                                   \
        for (int n_ = 0; n_ < 4; ++n_) {                                    \
            acc[n_] = __builtin_amdgcn_mfma_f32_16x16x32_bf16(ah_, BH[n_], acc[n_], 0, 0, 0); \
            acc[n_] = __builtin_amdgcn_mfma_f32_16x16x32_bf16(al_, BH[n_], acc[n_], 0, 0, 0); \
            acc[n_] = __builtin_amdgcn_mfma_f32_16x16x32_bf16(ah_, BL[n_], acc[n_], 0, 0, 0); \
        }                                                                   \
    } while (0)

    // ---- prologue ----
    LOAD_XJ(xe0, je0, xe1, je1, 0);
    LOAD_XJ(xo0, jo0, xo1, jo1, 1);
    LOAD_B(BH0, BL0, 0);
    WRITE_STAGE(0, xe0, je0, xe1, je1);      // chunk 0 -> buf 0

    // ---- main loop, unrolled x2 (even/odd named sets) ----
    for (int c = 0; c < NKS; c += 2) {
        // even half: compute chunk c
        {
            const int cl = (c + 2 < NKS) ? c + 2 : NKS - 1;
            LOAD_XJ(xe0, je0, xe1, je1, cl);            // chunk c+2 in flight
            const int kl = (c + 1 < NKS) ? c + 1 : NKS - 1;
            LOAD_B(BH1, BL1, kl);                       // B for c+1
            KSTEP(0, BH0, BL0);
            WRITE_STAGE(1, xo0, jo0, xo1, jo1);         // stage chunk c+1
        }
        // odd half: compute chunk c+1
        {
            const int cl = (c + 3 < NKS) ? c + 3 : NKS - 1;
            LOAD_XJ(xo0, jo0, xo1, jo1, cl);            // chunk c+3 in flight
            const int kl = (c + 2 < NKS) ? c + 2 : NKS - 1;
            LOAD_B(BH0, BL0, kl);                       // B for c+2
            KSTEP(1, BH1, BL1);
            WRITE_STAGE(0, xe0, je0, xe1, je1);         // stage chunk c+2
        }
    }

    // ---- epilogue: softmax + top-2 per token within 16-lane groups (R5, verified) ----
    const float b0 = bias[ln], b1 = bias[16 + ln], b2 = bias[32 + ln], b3 = bias[48 + ln];
    float* outw = out + tokBase * E;

#pragma unroll
    for (int r = 0; r < 4; ++r) {
        const float v0 = acc[0][r] + b0;
        const float v1 = acc[1][r] + b1;
        const float v2 = acc[2][r] + b2;
        const float v3 = acc[3][r] + b3;

        float p1 = v0; int i1 = ln;
        float p2 = -3.0e38f; int i2 = ln;
        if (v1 > p1)      { p2 = p1; i2 = i1; p1 = v1; i1 = 16 + ln; }
        else if (v1 > p2) { p2 = v1; i2 = 16 + ln; }
        if (v2 > p1)      { p2 = p1; i2 = i1; p1 = v2; i1 = 32 + ln; }
        else if (v2 > p2) { p2 = v2; i2 = 32 + ln; }
        if (v3 > p1)      { p2 = p1; i2 = i1; p1 = v3; i1 = 48 + ln; }
        else if (v3 > p2) { p2 = v3; i2 = 48 + ln; }

#pragma unroll
        for (int m = 1; m <= 8; m <<= 1) {
            const float q1 = __shfl_xor(p1, m, 16);
            const int   k1 = __shfl_xor(i1, m, 16);
            const float q2 = __shfl_xor(p2, m, 16);
            const int   k2 = __shfl_xor(i2, m, 16);
            const bool  bw = (q1 > p1) || (q1 == p1 && k1 < i1);
            const float f1 = bw ? q1 : p1;  const int fi1 = bw ? k1 : i1;
            const float lo = bw ? p1 : q1;  const int loi = bw ? i1 : k1;
            const float sn = bw ? q2 : p2;  const int sni = bw ? k2 : i2;
            const bool  rw = (lo > sn) || (lo == sn && loi < sni);
            p2 = rw ? lo : sn;  i2 = rw ? loi : sni;
            p1 = f1;            i1 = fi1;
        }

        float d = __expf(v0 - p1) + __expf(v1 - p1) + __expf(v2 - p1) + __expf(v3 - p1);
#pragma unroll
        for (int m = 1; m <= 8; m <<= 1) d += __shfl_xor(d, m, 16);

        const float inv = 1.f / d;
        const float w2  = __expf(p2 - p1) * inv;

        const size_t trow = (size_t)(g * 4 + r) * E;
        outw[trow +      ln] = (     ln == i1) ? inv : (     ln == i2) ? w2 : 0.f;
        outw[trow + 16 + ln] = (16 + ln == i1) ? inv : (16 + ln == i2) ? w2 : 0.f;
        outw[trow + 32 + ln] = (32 + ln == i1) ? inv : (32 + ln == i2) ? w2 : 0.f;
        outw[trow + 48 + ln] = (48 + ln == i1) ? inv : (48 + ln == i2) ? w2 : 0.f;
    }
}

extern "C" void kernel_launch(void* const* d_in, const int* in_sizes, int n_in,
                              void* d_out, int out_size, void* d_ws, size_t ws_size,
                              hipStream_t stream)
{
    const float* x   = (const float*)d_in[0];
    const float* jit = (const float*)d_in[1];
    const float* w   = (const float*)d_in[2];
    const float* b   = (const float*)d_in[3];
    float*       out = (float*)d_out;

    ushort* bpack = (ushort*)d_ws;   // 512 frags x 1 KB = 512 KB

    hipLaunchKernelGGL(wpack_kernel, dim3(64), dim3(256), 0, stream, w, bpack);

    const int n_tok = in_sizes[0] / H;   // 32768
    dim3 grid(n_tok / 64), block(256);
    hipLaunchKernelGGL(router_kernel, grid, block, 0, stream,
                       x, jit, bpack, b, out);
}